// Round 1
// baseline (489.308 us; speedup 1.0000x reference)
//
#include <hip/hip_runtime.h>
#include <math.h>

#define NVEC 131072
#define DIM 64
#define KCB 512

// d_out layout (floats): [0] loss | [1..8388608] quantized | [8388609] perplexity
//                        | [8388610 ..] encodings (131072 x 512)
// d_ws layout (bytes): [0,2048) u32 counts[512] | [2048] float loss_acc
//                      [4096,6144) float norms[512] | [8192, +512KB) int idx[131072]

__global__ __launch_bounds__(256) void vq_prep(const float* __restrict__ emb,
                                               float* __restrict__ norms,
                                               unsigned int* __restrict__ counts,
                                               float* __restrict__ loss_acc) {
    int t = blockIdx.x * 256 + threadIdx.x;
    if (t < KCB) {
        const float* e = emb + t * DIM;
        float s = 0.f;
#pragma unroll
        for (int d = 0; d < DIM; ++d) s = fmaf(e[d], e[d], s);
        norms[t] = s;
        counts[t] = 0u;
    }
    if (t == 0) *loss_acc = 0.f;
}

__global__ __launch_bounds__(256) void vq_main(const float* __restrict__ x,
                                               const float* __restrict__ emb,
                                               const float* __restrict__ norms,
                                               float* __restrict__ out,
                                               int* __restrict__ idx_out,
                                               unsigned int* __restrict__ counts,
                                               float* __restrict__ loss_acc) {
    float* __restrict__ qout = out + 1;
    float* __restrict__ enc  = out + 8388610;
    int b = blockIdx.x;
    int rb = b >> 1;

    if (b & 1) {
        // ---- fill role: zero the 268MB encodings region (overlaps with compute blocks)
        // 67108864 floats = 33554432 float2 (base is 8B aligned)
        float2* e2 = (float2*)enc;
        int tid = rb * 256 + threadIdx.x;   // 0..131071
        float2 z; z.x = 0.f; z.y = 0.f;
#pragma unroll 4
        for (int j = tid; j < 33554432; j += 131072) e2[j] = z;
        return;
    }

    // ---- compute role: one thread per input vector
    int i = rb * 256 + threadIdx.x;         // 0..131071
    const float4* xr = (const float4*)(x + (size_t)i * DIM);
    float4 xv[16];
#pragma unroll
    for (int j = 0; j < 16; ++j) xv[j] = xr[j];

    float xn;
    {
        float a0 = 0.f, a1 = 0.f, a2 = 0.f, a3 = 0.f;
#pragma unroll
        for (int j = 0; j < 16; ++j) {
            a0 = fmaf(xv[j].x, xv[j].x, a0);
            a1 = fmaf(xv[j].y, xv[j].y, a1);
            a2 = fmaf(xv[j].z, xv[j].z, a2);
            a3 = fmaf(xv[j].w, xv[j].w, a3);
        }
        xn = (a0 + a1) + (a2 + a3);
    }

    float best = 3.402823466e38f;
    int bi = 0;
    for (int k = 0; k < KCB; ++k) {
        const float* e = emb + k * DIM;     // wave-uniform address -> scalar loads
        float a0 = 0.f, a1 = 0.f, a2 = 0.f, a3 = 0.f;
#pragma unroll
        for (int j = 0; j < 16; ++j) {
            a0 = fmaf(xv[j].x, e[4 * j + 0], a0);
            a1 = fmaf(xv[j].y, e[4 * j + 1], a1);
            a2 = fmaf(xv[j].z, e[4 * j + 2], a2);
            a3 = fmaf(xv[j].w, e[4 * j + 3], a3);
        }
        float dot = (a0 + a1) + (a2 + a3);
        // mirror reference ordering: (||x||^2 - 2 x.e) + ||e||^2
        float dist = (xn - 2.f * dot) + norms[k];
        if (dist < best) { best = dist; bi = k; }
    }
    idx_out[i] = bi;

    // loss contribution: recompute directly as sum (x - e_best)^2 for accuracy
    float err;
    {
        const float4* eb = (const float4*)(emb + (size_t)bi * DIM);
        float a0 = 0.f, a1 = 0.f, a2 = 0.f, a3 = 0.f;
#pragma unroll
        for (int j = 0; j < 16; ++j) {
            float4 ev = eb[j];
            float d0 = xv[j].x - ev.x, d1 = xv[j].y - ev.y;
            float d2 = xv[j].z - ev.z, d3 = xv[j].w - ev.w;
            a0 = fmaf(d0, d0, a0);
            a1 = fmaf(d1, d1, a1);
            a2 = fmaf(d2, d2, a2);
            a3 = fmaf(d3, d3, a3);
        }
        err = (a0 + a1) + (a2 + a3);
    }
#pragma unroll
    for (int off = 32; off > 0; off >>= 1) err += __shfl_down(err, off);
    if ((threadIdx.x & 63) == 0) atomicAdd(loss_acc, err);

    // histogram + cooperative quantized write
    __shared__ unsigned int hist[KCB];
    __shared__ int sbi[256];
    sbi[threadIdx.x] = bi;
    for (int j = threadIdx.x; j < KCB; j += 256) hist[j] = 0u;
    __syncthreads();
    atomicAdd(&hist[bi], 1u);
    __syncthreads();
    for (int j = threadIdx.x; j < KCB; j += 256) {
        unsigned int c = hist[j];
        if (c) atomicAdd(&counts[j], c);
    }
    int base_row = rb * 256;
#pragma unroll 4
    for (int j = threadIdx.x; j < 256 * DIM; j += 256) {
        int r = j >> 6, c = j & 63;
        // qout is only 4B-aligned (out+1) -> dword stores, fully coalesced
        qout[(size_t)(base_row + r) * DIM + c] = emb[(size_t)sbi[r] * DIM + c];
    }
}

__global__ __launch_bounds__(256) void vq_scatter(const int* __restrict__ idx,
                                                  float* __restrict__ out) {
    float* enc = out + 8388610;
    int i = blockIdx.x * 256 + threadIdx.x;
    enc[(size_t)i * KCB + idx[i]] = 1.0f;
}

__global__ __launch_bounds__(512) void vq_final(const unsigned int* __restrict__ counts,
                                                const float* __restrict__ loss_acc,
                                                float* __restrict__ out) {
    __shared__ float red[512];
    int t = threadIdx.x;
    float p = (float)counts[t] * (1.0f / 131072.0f);
    red[t] = p * logf(p + 1e-10f);
    __syncthreads();
    for (int s = 256; s > 0; s >>= 1) {
        if (t < s) red[t] += red[t + s];
        __syncthreads();
    }
    if (t == 0) {
        out[8388609] = expf(-red[0]);
        out[0] = 1.25f * (*loss_acc) * (1.0f / 8388608.0f);
    }
}

extern "C" void kernel_launch(void* const* d_in, const int* in_sizes, int n_in,
                              void* d_out, int out_size, void* d_ws, size_t ws_size,
                              hipStream_t stream) {
    const float* x   = (const float*)d_in[0];
    const float* emb = (const float*)d_in[1];
    float* out = (float*)d_out;
    char* ws = (char*)d_ws;
    unsigned int* counts = (unsigned int*)ws;
    float* loss_acc = (float*)(ws + 2048);
    float* norms = (float*)(ws + 4096);
    int* idx = (int*)(ws + 8192);

    vq_prep<<<2, 256, 0, stream>>>(emb, norms, counts, loss_acc);
    vq_main<<<1024, 256, 0, stream>>>(x, emb, norms, out, idx, counts, loss_acc);
    vq_scatter<<<512, 256, 0, stream>>>(idx, out);
    vq_final<<<1, 512, 0, stream>>>(counts, loss_acc, out);
}

// Round 2
// 426.491 us; speedup vs baseline: 1.1473x; 1.1473x over previous
//
#include <hip/hip_runtime.h>
#include <math.h>

#define NVEC 131072
#define DIM 64
#define KCB 512
#define CHUNK 128   // codebook rows staged per LDS pass (32 KB)

// d_out layout (floats): [0] loss | [1..8388608] quantized | [8388609] perplexity
//                        | [8388610 ..] encodings (131072 x 512)
// d_ws layout (bytes): [0,2048) u32 counts[512] | [2048] float loss_acc
//                      [4096,6144) float norms[512] | [8192, +512KB) int idx[131072]

__global__ __launch_bounds__(256) void vq_prep(const float* __restrict__ emb,
                                               float* __restrict__ norms,
                                               unsigned int* __restrict__ counts,
                                               float* __restrict__ loss_acc) {
    int t = blockIdx.x * 256 + threadIdx.x;
    if (t < KCB) {
        const float* e = emb + t * DIM;
        float s = 0.f;
#pragma unroll
        for (int d = 0; d < DIM; ++d) s = fmaf(e[d], e[d], s);
        norms[t] = s;
        counts[t] = 0u;
    }
    if (t == 0) *loss_acc = 0.f;
}

__global__ __launch_bounds__(256) void vq_main(const float* __restrict__ x,
                                               const float* __restrict__ emb,
                                               const float* __restrict__ norms,
                                               float* __restrict__ out,
                                               int* __restrict__ idx_out,
                                               unsigned int* __restrict__ counts,
                                               float* __restrict__ loss_acc) {
    float* __restrict__ qout = out + 1;
    float* __restrict__ enc  = out + 8388610;
    int b = blockIdx.x;
    int rb = b >> 1;

    if (b & 1) {
        // ---- fill role: zero the 268MB encodings region (overlaps compute blocks)
        float2* e2 = (float2*)enc;   // base is 8B-aligned
        int tid = rb * 256 + threadIdx.x;   // 0..131071
        float2 z; z.x = 0.f; z.y = 0.f;
#pragma unroll 4
        for (int j = tid; j < 33554432; j += 131072) e2[j] = z;
        return;
    }

    // ---- compute role: one thread per input vector, codebook streamed via LDS
    __shared__ float lds_e[CHUNK * DIM];   // 32 KB
    __shared__ float lds_n[CHUNK];         // staged ||e||^2

    int i = rb * 256 + threadIdx.x;         // 0..131071
    const float4* xr = (const float4*)(x + (size_t)i * DIM);
    float4 xv[16];
#pragma unroll
    for (int j = 0; j < 16; ++j) xv[j] = xr[j];

    float xn;
    {
        float a0 = 0.f, a1 = 0.f, a2 = 0.f, a3 = 0.f;
#pragma unroll
        for (int j = 0; j < 16; ++j) {
            a0 = fmaf(xv[j].x, xv[j].x, a0);
            a1 = fmaf(xv[j].y, xv[j].y, a1);
            a2 = fmaf(xv[j].z, xv[j].z, a2);
            a3 = fmaf(xv[j].w, xv[j].w, a3);
        }
        xn = (a0 + a1) + (a2 + a3);
    }

    float best = 3.402823466e38f;
    int bi = 0;

    for (int c = 0; c < KCB / CHUNK; ++c) {
        int k0 = c * CHUNK;
        __syncthreads();
        // cooperative coalesced staging: CHUNK*DIM floats = 2048 float4
        {
            const float4* src = (const float4*)(emb + (size_t)k0 * DIM);
            float4* dst = (float4*)lds_e;
#pragma unroll
            for (int j = 0; j < (CHUNK * DIM / 4) / 256; ++j)
                dst[threadIdx.x + j * 256] = src[threadIdx.x + j * 256];
            if (threadIdx.x < CHUNK) lds_n[threadIdx.x] = norms[k0 + threadIdx.x];
        }
        __syncthreads();

        for (int k = 0; k < CHUNK; ++k) {
            const float4* er = (const float4*)&lds_e[k * DIM];  // broadcast reads
            float a0 = 0.f, a1 = 0.f, a2 = 0.f, a3 = 0.f;
#pragma unroll
            for (int j = 0; j < 16; ++j) {
                float4 ev = er[j];
                a0 = fmaf(xv[j].x, ev.x, a0);
                a1 = fmaf(xv[j].y, ev.y, a1);
                a2 = fmaf(xv[j].z, ev.z, a2);
                a3 = fmaf(xv[j].w, ev.w, a3);
            }
            float dot = (a0 + a1) + (a2 + a3);
            // mirror reference ordering: (||x||^2 - 2 x.e) + ||e||^2
            float dist = (xn - 2.f * dot) + lds_n[k];
            if (dist < best) { best = dist; bi = k0 + k; }
        }
    }
    idx_out[i] = bi;

    // loss contribution: recompute directly as sum (x - e_best)^2
    float err;
    {
        const float4* eb = (const float4*)(emb + (size_t)bi * DIM);
        float a0 = 0.f, a1 = 0.f, a2 = 0.f, a3 = 0.f;
#pragma unroll
        for (int j = 0; j < 16; ++j) {
            float4 ev = eb[j];
            float d0 = xv[j].x - ev.x, d1 = xv[j].y - ev.y;
            float d2 = xv[j].z - ev.z, d3 = xv[j].w - ev.w;
            a0 = fmaf(d0, d0, a0);
            a1 = fmaf(d1, d1, a1);
            a2 = fmaf(d2, d2, a2);
            a3 = fmaf(d3, d3, a3);
        }
        err = (a0 + a1) + (a2 + a3);
    }
#pragma unroll
    for (int off = 32; off > 0; off >>= 1) err += __shfl_down(err, off);
    if ((threadIdx.x & 63) == 0) atomicAdd(loss_acc, err);

    // histogram + cooperative quantized write
    __shared__ unsigned int hist[KCB];
    __shared__ int sbi[256];
    sbi[threadIdx.x] = bi;
    for (int j = threadIdx.x; j < KCB; j += 256) hist[j] = 0u;
    __syncthreads();
    atomicAdd(&hist[bi], 1u);
    __syncthreads();
    for (int j = threadIdx.x; j < KCB; j += 256) {
        unsigned int c = hist[j];
        if (c) atomicAdd(&counts[j], c);
    }
    int base_row = rb * 256;
#pragma unroll 4
    for (int j = threadIdx.x; j < 256 * DIM; j += 256) {
        int r = j >> 6, cc = j & 63;
        qout[(size_t)(base_row + r) * DIM + cc] = emb[(size_t)sbi[r] * DIM + cc];
    }
}

__global__ __launch_bounds__(256) void vq_scatter(const int* __restrict__ idx,
                                                  float* __restrict__ out) {
    float* enc = out + 8388610;
    int i = blockIdx.x * 256 + threadIdx.x;
    enc[(size_t)i * KCB + idx[i]] = 1.0f;
}

__global__ __launch_bounds__(512) void vq_final(const unsigned int* __restrict__ counts,
                                                const float* __restrict__ loss_acc,
                                                float* __restrict__ out) {
    __shared__ float red[512];
    int t = threadIdx.x;
    float p = (float)counts[t] * (1.0f / 131072.0f);
    red[t] = p * logf(p + 1e-10f);
    __syncthreads();
    for (int s = 256; s > 0; s >>= 1) {
        if (t < s) red[t] += red[t + s];
        __syncthreads();
    }
    if (t == 0) {
        out[8388609] = expf(-red[0]);
        out[0] = 1.25f * (*loss_acc) * (1.0f / 8388608.0f);
    }
}

extern "C" void kernel_launch(void* const* d_in, const int* in_sizes, int n_in,
                              void* d_out, int out_size, void* d_ws, size_t ws_size,
                              hipStream_t stream) {
    const float* x   = (const float*)d_in[0];
    const float* emb = (const float*)d_in[1];
    float* out = (float*)d_out;
    char* ws = (char*)d_ws;
    unsigned int* counts = (unsigned int*)ws;
    float* loss_acc = (float*)(ws + 2048);
    float* norms = (float*)(ws + 4096);
    int* idx = (int*)(ws + 8192);

    vq_prep<<<2, 256, 0, stream>>>(emb, norms, counts, loss_acc);
    vq_main<<<1024, 256, 0, stream>>>(x, emb, norms, out, idx, counts, loss_acc);
    vq_scatter<<<512, 256, 0, stream>>>(idx, out);
    vq_final<<<1, 512, 0, stream>>>(counts, loss_acc, out);
}

// Round 3
// 343.001 us; speedup vs baseline: 1.4265x; 1.2434x over previous
//
#include <hip/hip_runtime.h>
#include <math.h>

#define NVEC 131072
#define DIM 64
#define KCB 512
#define CHUNK 128   // codebook rows staged per LDS pass (32 KB)

// d_out layout (floats): [0] loss | [1..8388608] quantized | [8388609] perplexity
//                        | [8388610 ..] encodings (131072 x 512)
// d_ws layout (bytes): [0,2048) u32 counts[512] | [2048] float loss_acc
//                      [4096,6144) float norms[512] | [8192, +512KB) int idx[131072]

__global__ __launch_bounds__(256) void vq_prep(const float* __restrict__ emb,
                                               float* __restrict__ norms,
                                               unsigned int* __restrict__ counts,
                                               float* __restrict__ loss_acc) {
    int t = blockIdx.x * 256 + threadIdx.x;
    if (t < KCB) {
        const float* e = emb + t * DIM;
        float s = 0.f;
#pragma unroll
        for (int d = 0; d < DIM; ++d) s = fmaf(e[d], e[d], s);
        norms[t] = s;
        counts[t] = 0u;
    }
    if (t == 0) *loss_acc = 0.f;
}

__global__ __launch_bounds__(256) void vq_main(const float* __restrict__ x,
                                               const float* __restrict__ emb,
                                               const float* __restrict__ norms,
                                               float* __restrict__ out,
                                               int* __restrict__ idx_out,
                                               unsigned int* __restrict__ counts,
                                               float* __restrict__ loss_acc) {
    float* __restrict__ qout = out + 1;
    float* __restrict__ enc  = out + 8388610;
    int b = blockIdx.x;
    int rb = b >> 1;

    if (b & 1) {
        // ---- fill role: zero the 268MB encodings region (overlaps compute blocks)
        float2* e2 = (float2*)enc;   // base is 8B-aligned
        int tid = rb * 256 + threadIdx.x;   // 0..65535
        float2 z; z.x = 0.f; z.y = 0.f;
#pragma unroll 4
        for (int j = tid; j < 33554432; j += 65536) e2[j] = z;
        return;
    }

    // ---- compute role: TWO x-vectors per thread (512 per block), e streamed via LDS
    __shared__ float lds_e[CHUNK * DIM];   // 32 KB
    __shared__ float lds_n[CHUNK];

    int iA = rb * 512 + threadIdx.x;        // rows iA and iA+256
    int iB = iA + 256;
    const float4* xrA = (const float4*)(x + (size_t)iA * DIM);
    const float4* xrB = (const float4*)(x + (size_t)iB * DIM);
    float4 xA[16], xB[16];
#pragma unroll
    for (int j = 0; j < 16; ++j) xA[j] = xrA[j];
#pragma unroll
    for (int j = 0; j < 16; ++j) xB[j] = xrB[j];

    float xnA, xnB;
    {
        float a0 = 0.f, a1 = 0.f, a2 = 0.f, a3 = 0.f;
        float b0 = 0.f, b1 = 0.f, b2 = 0.f, b3 = 0.f;
#pragma unroll
        for (int j = 0; j < 16; ++j) {
            a0 = fmaf(xA[j].x, xA[j].x, a0);
            a1 = fmaf(xA[j].y, xA[j].y, a1);
            a2 = fmaf(xA[j].z, xA[j].z, a2);
            a3 = fmaf(xA[j].w, xA[j].w, a3);
            b0 = fmaf(xB[j].x, xB[j].x, b0);
            b1 = fmaf(xB[j].y, xB[j].y, b1);
            b2 = fmaf(xB[j].z, xB[j].z, b2);
            b3 = fmaf(xB[j].w, xB[j].w, b3);
        }
        xnA = (a0 + a1) + (a2 + a3);
        xnB = (b0 + b1) + (b2 + b3);
    }

    float bestA = 3.402823466e38f, bestB = 3.402823466e38f;
    int biA = 0, biB = 0;

    for (int c = 0; c < KCB / CHUNK; ++c) {
        int k0 = c * CHUNK;
        __syncthreads();
        {
            const float4* src = (const float4*)(emb + (size_t)k0 * DIM);
            float4* dst = (float4*)lds_e;
#pragma unroll
            for (int j = 0; j < (CHUNK * DIM / 4) / 256; ++j)
                dst[threadIdx.x + j * 256] = src[threadIdx.x + j * 256];
            if (threadIdx.x < CHUNK) lds_n[threadIdx.x] = norms[k0 + threadIdx.x];
        }
        __syncthreads();

#pragma unroll 2
        for (int k = 0; k < CHUNK; ++k) {
            const float4* er = (const float4*)&lds_e[k * DIM];  // broadcast reads
            float a0 = 0.f, a1 = 0.f, a2 = 0.f, a3 = 0.f;
            float b0 = 0.f, b1 = 0.f, b2 = 0.f, b3 = 0.f;
#pragma unroll
            for (int j = 0; j < 16; ++j) {
                float4 ev = er[j];
                a0 = fmaf(xA[j].x, ev.x, a0);
                a1 = fmaf(xA[j].y, ev.y, a1);
                a2 = fmaf(xA[j].z, ev.z, a2);
                a3 = fmaf(xA[j].w, ev.w, a3);
                b0 = fmaf(xB[j].x, ev.x, b0);
                b1 = fmaf(xB[j].y, ev.y, b1);
                b2 = fmaf(xB[j].z, ev.z, b2);
                b3 = fmaf(xB[j].w, ev.w, b3);
            }
            float dotA = (a0 + a1) + (a2 + a3);
            float dotB = (b0 + b1) + (b2 + b3);
            float en = lds_n[k];
            // mirror reference ordering: (||x||^2 - 2 x.e) + ||e||^2
            // fmaf(-2,dot,xn) == xn - 2*dot exactly (2*dot is exact in fp32)
            float distA = fmaf(-2.f, dotA, xnA) + en;
            float distB = fmaf(-2.f, dotB, xnB) + en;
            if (distA < bestA) { bestA = distA; biA = k0 + k; }
            if (distB < bestB) { bestB = distB; biB = k0 + k; }
        }
    }
    idx_out[iA] = biA;
    idx_out[iB] = biB;

    // loss contribution: recompute directly as sum (x - e_best)^2
    float err;
    {
        const float4* eA = (const float4*)(emb + (size_t)biA * DIM);
        const float4* eB = (const float4*)(emb + (size_t)biB * DIM);
        float a0 = 0.f, a1 = 0.f, a2 = 0.f, a3 = 0.f;
#pragma unroll
        for (int j = 0; j < 16; ++j) {
            float4 ev = eA[j];
            float d0 = xA[j].x - ev.x, d1 = xA[j].y - ev.y;
            float d2 = xA[j].z - ev.z, d3 = xA[j].w - ev.w;
            a0 = fmaf(d0, d0, a0);
            a1 = fmaf(d1, d1, a1);
            a2 = fmaf(d2, d2, a2);
            a3 = fmaf(d3, d3, a3);
            float4 fv = eB[j];
            float e0 = xB[j].x - fv.x, e1 = xB[j].y - fv.y;
            float e2 = xB[j].z - fv.z, e3 = xB[j].w - fv.w;
            a0 = fmaf(e0, e0, a0);
            a1 = fmaf(e1, e1, a1);
            a2 = fmaf(e2, e2, a2);
            a3 = fmaf(e3, e3, a3);
        }
        err = (a0 + a1) + (a2 + a3);
    }
#pragma unroll
    for (int off = 32; off > 0; off >>= 1) err += __shfl_down(err, off);
    if ((threadIdx.x & 63) == 0) atomicAdd(loss_acc, err);

    // histogram + cooperative quantized write
    __shared__ unsigned int hist[KCB];
    __shared__ int sbi[512];
    sbi[threadIdx.x] = biA;
    sbi[threadIdx.x + 256] = biB;
    for (int j = threadIdx.x; j < KCB; j += 256) hist[j] = 0u;
    __syncthreads();
    atomicAdd(&hist[biA], 1u);
    atomicAdd(&hist[biB], 1u);
    __syncthreads();
    for (int j = threadIdx.x; j < KCB; j += 256) {
        unsigned int c = hist[j];
        if (c) atomicAdd(&counts[j], c);
    }
    int base_row = rb * 512;
#pragma unroll 4
    for (int j = threadIdx.x; j < 512 * DIM; j += 256) {
        int r = j >> 6, cc = j & 63;
        qout[(size_t)(base_row + r) * DIM + cc] = emb[(size_t)sbi[r] * DIM + cc];
    }
}

__global__ __launch_bounds__(256) void vq_scatter(const int* __restrict__ idx,
                                                  float* __restrict__ out) {
    float* enc = out + 8388610;
    int i = blockIdx.x * 256 + threadIdx.x;
    enc[(size_t)i * KCB + idx[i]] = 1.0f;
}

__global__ __launch_bounds__(512) void vq_final(const unsigned int* __restrict__ counts,
                                                const float* __restrict__ loss_acc,
                                                float* __restrict__ out) {
    __shared__ float red[512];
    int t = threadIdx.x;
    float p = (float)counts[t] * (1.0f / 131072.0f);
    red[t] = p * logf(p + 1e-10f);
    __syncthreads();
    for (int s = 256; s > 0; s >>= 1) {
        if (t < s) red[t] += red[t + s];
        __syncthreads();
    }
    if (t == 0) {
        out[8388609] = expf(-red[0]);
        out[0] = 1.25f * (*loss_acc) * (1.0f / 8388608.0f);
    }
}

extern "C" void kernel_launch(void* const* d_in, const int* in_sizes, int n_in,
                              void* d_out, int out_size, void* d_ws, size_t ws_size,
                              hipStream_t stream) {
    const float* x   = (const float*)d_in[0];
    const float* emb = (const float*)d_in[1];
    float* out = (float*)d_out;
    char* ws = (char*)d_ws;
    unsigned int* counts = (unsigned int*)ws;
    float* loss_acc = (float*)(ws + 2048);
    float* norms = (float*)(ws + 4096);
    int* idx = (int*)(ws + 8192);

    vq_prep<<<2, 256, 0, stream>>>(emb, norms, counts, loss_acc);
    vq_main<<<512, 256, 0, stream>>>(x, emb, norms, out, idx, counts, loss_acc);
    vq_scatter<<<512, 256, 0, stream>>>(idx, out);
    vq_final<<<1, 512, 0, stream>>>(counts, loss_acc, out);
}

// Round 4
// 238.725 us; speedup vs baseline: 2.0497x; 1.4368x over previous
//
#include <hip/hip_runtime.h>
#include <math.h>

#define NVEC 131072
#define DIM 64
#define KCB 512
#define CHUNK 128     // codebook rows staged per LDS pass (32 KB)
#define KHALF 256     // k-rows per k-partition

// d_out layout (floats): [0] loss | [1..8388608] quantized | [8388609] perplexity
//                        | [8388610 ..] encodings (131072 x 512)
// d_ws layout (bytes):
//   [0,2048)        u32 counts[512]
//   [2048]          float loss_acc
//   [4096,6144)     float norms[512]
//   [8192, +512KB)  float dist0[131072]
//   [532480, ...)   float dist1[131072]
//   [1056768, ...)  int   idx0[131072]
//   [1581056, ...)  int   idx1[131072]

__global__ __launch_bounds__(256) void vq_prep(const float* __restrict__ emb,
                                               float* __restrict__ norms,
                                               unsigned int* __restrict__ counts,
                                               float* __restrict__ loss_acc) {
    int t = blockIdx.x * 256 + threadIdx.x;
    if (t < KCB) {
        const float* e = emb + t * DIM;
        float s = 0.f;
#pragma unroll
        for (int d = 0; d < DIM; ++d) s = fmaf(e[d], e[d], s);
        norms[t] = s;
        counts[t] = 0u;
    }
    if (t == 0) *loss_acc = 0.f;
}

__global__ __launch_bounds__(256) void vq_main(const float* __restrict__ x,
                                               const float* __restrict__ emb,
                                               const float* __restrict__ norms,
                                               float* __restrict__ out,
                                               float* __restrict__ dists,
                                               int* __restrict__ idxs) {
    float* __restrict__ enc = out + 8388610;
    int b = blockIdx.x;

    if (b % 3 == 2) {
        // ---- fill role: zero the 268MB encodings region (overlaps compute blocks)
        float2* e2 = (float2*)enc;   // base is 8B-aligned
        int tid = (b / 3) * 256 + threadIdx.x;   // 0..65535
        float2 z; z.x = 0.f; z.y = 0.f;
#pragma unroll 4
        for (int j = tid; j < 33554432; j += 65536) e2[j] = z;
        return;
    }

    // ---- compute role: 512 blocks; each covers 512 vectors x one k-half.
    int cidx = (b / 3) * 2 + (b % 3);   // 0..511
    int kpart = cidx & 1;
    int vg = cidx >> 1;                  // 0..255
    int kbase = kpart * KHALF;

    __shared__ float lds_e[CHUNK * DIM];   // 32 KB
    __shared__ float lds_n[CHUNK];

    int iA = vg * 512 + threadIdx.x;     // rows iA and iA+256
    int iB = iA + 256;
    const float4* xrA = (const float4*)(x + (size_t)iA * DIM);
    const float4* xrB = (const float4*)(x + (size_t)iB * DIM);
    float4 xA[16], xB[16];
#pragma unroll
    for (int j = 0; j < 16; ++j) xA[j] = xrA[j];
#pragma unroll
    for (int j = 0; j < 16; ++j) xB[j] = xrB[j];

    float xnA, xnB;
    {
        float a0 = 0.f, a1 = 0.f, a2 = 0.f, a3 = 0.f;
        float b0 = 0.f, b1 = 0.f, b2 = 0.f, b3 = 0.f;
#pragma unroll
        for (int j = 0; j < 16; ++j) {
            a0 = fmaf(xA[j].x, xA[j].x, a0);
            a1 = fmaf(xA[j].y, xA[j].y, a1);
            a2 = fmaf(xA[j].z, xA[j].z, a2);
            a3 = fmaf(xA[j].w, xA[j].w, a3);
            b0 = fmaf(xB[j].x, xB[j].x, b0);
            b1 = fmaf(xB[j].y, xB[j].y, b1);
            b2 = fmaf(xB[j].z, xB[j].z, b2);
            b3 = fmaf(xB[j].w, xB[j].w, b3);
        }
        xnA = (a0 + a1) + (a2 + a3);
        xnB = (b0 + b1) + (b2 + b3);
    }

    float bestA = 3.402823466e38f, bestB = 3.402823466e38f;
    int biA = kbase, biB = kbase;

    for (int c = 0; c < KHALF / CHUNK; ++c) {
        int k0 = kbase + c * CHUNK;
        __syncthreads();
        {
            const float4* src = (const float4*)(emb + (size_t)k0 * DIM);
            float4* dst = (float4*)lds_e;
#pragma unroll
            for (int j = 0; j < (CHUNK * DIM / 4) / 256; ++j)
                dst[threadIdx.x + j * 256] = src[threadIdx.x + j * 256];
            if (threadIdx.x < CHUNK) lds_n[threadIdx.x] = norms[k0 + threadIdx.x];
        }
        __syncthreads();

#pragma unroll 2
        for (int k = 0; k < CHUNK; ++k) {
            const float4* er = (const float4*)&lds_e[k * DIM];  // broadcast reads
            float a0 = 0.f, a1 = 0.f, a2 = 0.f, a3 = 0.f;
            float b0 = 0.f, b1 = 0.f, b2 = 0.f, b3 = 0.f;
#pragma unroll
            for (int j = 0; j < 16; ++j) {
                float4 ev = er[j];
                a0 = fmaf(xA[j].x, ev.x, a0);
                a1 = fmaf(xA[j].y, ev.y, a1);
                a2 = fmaf(xA[j].z, ev.z, a2);
                a3 = fmaf(xA[j].w, ev.w, a3);
                b0 = fmaf(xB[j].x, ev.x, b0);
                b1 = fmaf(xB[j].y, ev.y, b1);
                b2 = fmaf(xB[j].z, ev.z, b2);
                b3 = fmaf(xB[j].w, ev.w, b3);
            }
            float dotA = (a0 + a1) + (a2 + a3);
            float dotB = (b0 + b1) + (b2 + b3);
            float en = lds_n[k];
            // mirror reference ordering: (||x||^2 - 2 x.e) + ||e||^2
            float distA = fmaf(-2.f, dotA, xnA) + en;
            float distB = fmaf(-2.f, dotB, xnB) + en;
            if (distA < bestA) { bestA = distA; biA = k0 + k; }
            if (distB < bestB) { bestB = distB; biB = k0 + k; }
        }
    }
    float* dist_p = dists + (size_t)kpart * NVEC;
    int* idx_p = idxs + (size_t)kpart * NVEC;
    dist_p[iA] = bestA;
    dist_p[iB] = bestB;
    idx_p[iA] = biA;
    idx_p[iB] = biB;
}

// merge the two k-partitions + full epilogue (loss, hist, quantized, one-hot)
__global__ __launch_bounds__(256) void vq_merge(const float* __restrict__ x,
                                                const float* __restrict__ emb,
                                                const float* __restrict__ dists,
                                                const int* __restrict__ idxs,
                                                float* __restrict__ out,
                                                unsigned int* __restrict__ counts,
                                                float* __restrict__ loss_acc) {
    float* __restrict__ qout = out + 1;
    float* __restrict__ enc  = out + 8388610;
    int i = blockIdx.x * 256 + threadIdx.x;

    float d0 = dists[i];
    float d1 = dists[NVEC + i];
    int i0 = idxs[i];
    int i1 = idxs[NVEC + i];
    // np.argmin keeps the FIRST minimum -> lower k wins ties; part0 has lower k.
    int bi = (d1 < d0) ? i1 : i0;

    // loss contribution: sum (x - e_best)^2
    float err;
    {
        const float4* xr = (const float4*)(x + (size_t)i * DIM);
        const float4* eb = (const float4*)(emb + (size_t)bi * DIM);
        float a0 = 0.f, a1 = 0.f, a2 = 0.f, a3 = 0.f;
#pragma unroll
        for (int j = 0; j < 16; ++j) {
            float4 xv = xr[j];
            float4 ev = eb[j];
            float e0 = xv.x - ev.x, e1 = xv.y - ev.y;
            float e2 = xv.z - ev.z, e3 = xv.w - ev.w;
            a0 = fmaf(e0, e0, a0);
            a1 = fmaf(e1, e1, a1);
            a2 = fmaf(e2, e2, a2);
            a3 = fmaf(e3, e3, a3);
        }
        err = (a0 + a1) + (a2 + a3);
    }
#pragma unroll
    for (int off = 32; off > 0; off >>= 1) err += __shfl_down(err, off);
    if ((threadIdx.x & 63) == 0) atomicAdd(loss_acc, err);

    // histogram + cooperative quantized write
    __shared__ unsigned int hist[KCB];
    __shared__ int sbi[256];
    sbi[threadIdx.x] = bi;
    for (int j = threadIdx.x; j < KCB; j += 256) hist[j] = 0u;
    __syncthreads();
    atomicAdd(&hist[bi], 1u);
    __syncthreads();
    for (int j = threadIdx.x; j < KCB; j += 256) {
        unsigned int c = hist[j];
        if (c) atomicAdd(&counts[j], c);
    }
    int base_row = blockIdx.x * 256;
#pragma unroll 4
    for (int j = threadIdx.x; j < 256 * DIM; j += 256) {
        int r = j >> 6, cc = j & 63;
        qout[(size_t)(base_row + r) * DIM + cc] = emb[(size_t)sbi[r] * DIM + cc];
    }

    // one-hot scatter (encodings already zeroed by fill role in vq_main)
    enc[(size_t)i * KCB + bi] = 1.0f;
}

__global__ __launch_bounds__(512) void vq_final(const unsigned int* __restrict__ counts,
                                                const float* __restrict__ loss_acc,
                                                float* __restrict__ out) {
    __shared__ float red[512];
    int t = threadIdx.x;
    float p = (float)counts[t] * (1.0f / 131072.0f);
    red[t] = p * logf(p + 1e-10f);
    __syncthreads();
    for (int s = 256; s > 0; s >>= 1) {
        if (t < s) red[t] += red[t + s];
        __syncthreads();
    }
    if (t == 0) {
        out[8388609] = expf(-red[0]);
        out[0] = 1.25f * (*loss_acc) * (1.0f / 8388608.0f);
    }
}

extern "C" void kernel_launch(void* const* d_in, const int* in_sizes, int n_in,
                              void* d_out, int out_size, void* d_ws, size_t ws_size,
                              hipStream_t stream) {
    const float* x   = (const float*)d_in[0];
    const float* emb = (const float*)d_in[1];
    float* out = (float*)d_out;
    char* ws = (char*)d_ws;
    unsigned int* counts = (unsigned int*)ws;
    float* loss_acc = (float*)(ws + 2048);
    float* norms = (float*)(ws + 4096);
    float* dists = (float*)(ws + 8192);                 // [2][131072] floats
    int* idxs = (int*)(ws + 8192 + 2 * NVEC * 4);       // [2][131072] ints

    vq_prep<<<2, 256, 0, stream>>>(emb, norms, counts, loss_acc);
    vq_main<<<768, 256, 0, stream>>>(x, emb, norms, out, dists, idxs);
    vq_merge<<<512, 256, 0, stream>>>(x, emb, dists, idxs, out, counts, loss_acc);
    vq_final<<<1, 512, 0, stream>>>(counts, loss_acc, out);
}

// Round 5
// 200.410 us; speedup vs baseline: 2.4415x; 1.1912x over previous
//
#include <hip/hip_runtime.h>
#include <math.h>

#define NVEC 131072
#define DIM 64
#define KCB 512
#define FLT_BIG 3.402823466e38f

typedef __attribute__((ext_vector_type(8))) short bf16x8;
typedef __attribute__((ext_vector_type(4))) float f32x4;

// d_out layout (floats): [0] loss | [1..8388608] quantized | [8388609] perplexity
//                        | [8388610 ..] encodings (131072 x 512)
// d_ws layout (bytes):
//   [0,2048)         u32 counts[512]
//   [2048]           float loss_acc
//   [4096,6144)      float norms[512]
//   [8192, +1MB)     int2 cand[131072]          (top-2 candidate indices)
//   [1056768, +128K) ushort e_bf[512][128]      (row: eh[64] | el[64])

__device__ inline unsigned int bf16_rne(float f) {
    unsigned int u = __float_as_uint(f);
    u += 0x7fffu + ((u >> 16) & 1u);
    return u >> 16;
}

__device__ inline void split_frag(float4 p0, float4 p1, bf16x8& hi, bf16x8& lo) {
    union { bf16x8 v; unsigned int u[4]; } H, L;
    float f[8] = {p0.x, p0.y, p0.z, p0.w, p1.x, p1.y, p1.z, p1.w};
    unsigned int h[8];
    float r[8];
#pragma unroll
    for (int j = 0; j < 8; ++j) {
        h[j] = bf16_rne(f[j]);
        r[j] = f[j] - __uint_as_float(h[j] << 16);
    }
#pragma unroll
    for (int j = 0; j < 4; ++j) {
        H.u[j] = h[2 * j] | (h[2 * j + 1] << 16);
        L.u[j] = bf16_rne(r[2 * j]) | (bf16_rne(r[2 * j + 1]) << 16);
    }
    hi = H.v;
    lo = L.v;
}

// merge two top-2 lists across lane pairs (k-subsets are disjoint)
__device__ inline void merge_top2(float& d1, int& i1, float& d2, int& i2) {
#pragma unroll
    for (int m = 16; m <= 32; m <<= 1) {
        float e1 = __shfl_xor(d1, m), e2 = __shfl_xor(d2, m);
        int j1 = __shfl_xor(i1, m), j2 = __shfl_xor(i2, m);
        bool af = (d1 < e1) || (d1 == e1 && i1 < j1);
        float w2 = af ? d2 : e2; int w2i = af ? i2 : j2;   // winner's runner-up
        float lb = af ? e1 : d1; int lbi = af ? j1 : i1;   // loser's best
        bool bs = (w2 < lb) || (w2 == lb && w2i < lbi);
        d1 = af ? d1 : e1; i1 = af ? i1 : j1;
        d2 = bs ? w2 : lb; i2 = bs ? w2i : lbi;
    }
}

// prep: norms (fp32), bf16 hi/lo codebook, zero counts/loss
__global__ __launch_bounds__(256) void vq_prep(const float* __restrict__ emb,
                                               float* __restrict__ norms,
                                               unsigned short* __restrict__ e_bf,
                                               unsigned int* __restrict__ counts,
                                               float* __restrict__ loss_acc) {
    int gid = blockIdx.x * 256 + threadIdx.x;   // 0..2047
    int row = gid >> 2, part = gid & 3, d0 = part * 16;
    const float* e = emb + row * DIM + d0;
    float s = 0.f;
#pragma unroll
    for (int d = 0; d < 16; ++d) s = fmaf(e[d], e[d], s);
    s += __shfl_xor(s, 1);
    s += __shfl_xor(s, 2);
    if (part == 0) norms[row] = s;
#pragma unroll
    for (int d = 0; d < 16; ++d) {
        float f = e[d];
        unsigned int h = bf16_rne(f);
        float r = f - __uint_as_float(h << 16);
        e_bf[row * 128 + d0 + d] = (unsigned short)h;
        e_bf[row * 128 + 64 + d0 + d] = (unsigned short)bf16_rne(r);
    }
    if (gid < KCB) counts[gid] = 0u;
    if (gid == 0) *loss_acc = 0.f;
}

__global__ __launch_bounds__(256, 4) void vq_main(const float* __restrict__ x,
                                                  const unsigned short* __restrict__ e_bf,
                                                  const float* __restrict__ norms,
                                                  float* __restrict__ out,
                                                  int2* __restrict__ cand) {
    float* __restrict__ enc = out + 8388610;
    int b = blockIdx.x;

    if (b & 1) {
        // ---- fill role: zero the 268MB encodings region (overlaps compute)
        // enc is 8B-aligned; enc+2 is 16B-aligned -> float4 body + head/tail
        float4* e4 = (float4*)(enc + 2);
        int fid = (b >> 1) * 256 + threadIdx.x;    // 0..262143
        float4 z = {0.f, 0.f, 0.f, 0.f};
#pragma unroll 4
        for (int j = fid; j < 16777215; j += 262144) e4[j] = z;
        if (b == 1 && threadIdx.x == 0) {
            enc[0] = 0.f; enc[1] = 0.f;
            enc[67108862] = 0.f; enc[67108863] = 0.f;
        }
        return;
    }

    // ---- compute role: per wave, 32 x-rows (two 16-col groups) x all 512 k
    int cidx = b >> 1;                 // 0..1023
    int wave = threadIdx.x >> 6;
    int lane = threadIdx.x & 63;
    int nl = lane & 15, kg = lane >> 4;
    int rowA = cidx * 128 + wave * 32 + nl;
    int rowB = rowA + 16;

    // B-frags (x side): lane col = x-row, k = kg*8+e (+32 per kslice)
    bf16x8 xhA[2], xlA[2], xhB[2], xlB[2];
    {
        const float* xA = x + (size_t)rowA * DIM;
        const float* xB = x + (size_t)rowB * DIM;
#pragma unroll
        for (int ks = 0; ks < 2; ++ks) {
            const float4* pA = (const float4*)(xA + ks * 32 + kg * 8);
            const float4* pB = (const float4*)(xB + ks * 32 + kg * 8);
            split_frag(pA[0], pA[1], xhA[ks], xlA[ks]);
            split_frag(pB[0], pB[1], xhB[ks], xlB[ks]);
        }
    }

    float d1A = FLT_BIG, d2A = FLT_BIG, d1B = FLT_BIG, d2B = FLT_BIG;
    int i1A = 0, i2A = 0, i1B = 0, i2B = 0;

    const unsigned short* ebl = e_bf + (size_t)nl * 128;
#pragma unroll 2
    for (int t = 0; t < 32; ++t) {
        const unsigned short* eb = ebl + t * 2048;  // codebook row t*16+nl
        bf16x8 eh0 = *(const bf16x8*)(eb + kg * 8);
        bf16x8 eh1 = *(const bf16x8*)(eb + 32 + kg * 8);
        bf16x8 el0 = *(const bf16x8*)(eb + 64 + kg * 8);
        bf16x8 el1 = *(const bf16x8*)(eb + 96 + kg * 8);

        f32x4 aA = {}, aB = {};
        // dot = xh*eh + xh*el + xl*eh  (A = e-side, B = x-side)
        aA = __builtin_amdgcn_mfma_f32_16x16x32_bf16(eh0, xhA[0], aA, 0, 0, 0);
        aA = __builtin_amdgcn_mfma_f32_16x16x32_bf16(eh1, xhA[1], aA, 0, 0, 0);
        aA = __builtin_amdgcn_mfma_f32_16x16x32_bf16(el0, xhA[0], aA, 0, 0, 0);
        aA = __builtin_amdgcn_mfma_f32_16x16x32_bf16(el1, xhA[1], aA, 0, 0, 0);
        aA = __builtin_amdgcn_mfma_f32_16x16x32_bf16(eh0, xlA[0], aA, 0, 0, 0);
        aA = __builtin_amdgcn_mfma_f32_16x16x32_bf16(eh1, xlA[1], aA, 0, 0, 0);

        aB = __builtin_amdgcn_mfma_f32_16x16x32_bf16(eh0, xhB[0], aB, 0, 0, 0);
        aB = __builtin_amdgcn_mfma_f32_16x16x32_bf16(eh1, xhB[1], aB, 0, 0, 0);
        aB = __builtin_amdgcn_mfma_f32_16x16x32_bf16(el0, xhB[0], aB, 0, 0, 0);
        aB = __builtin_amdgcn_mfma_f32_16x16x32_bf16(el1, xhB[1], aB, 0, 0, 0);
        aB = __builtin_amdgcn_mfma_f32_16x16x32_bf16(eh0, xlB[0], aB, 0, 0, 0);
        aB = __builtin_amdgcn_mfma_f32_16x16x32_bf16(eh1, xlB[1], aB, 0, 0, 0);

        // C/D: col=lane&15 (x-row), row=(lane>>4)*4+reg (e-idx) [m89-verified]
        int krow0 = t * 16 + kg * 4;
#pragma unroll
        for (int r = 0; r < 4; ++r) {
            float en = norms[krow0 + r];
            int ki = krow0 + r;
            float dA = fmaf(-2.f, aA[r], en);   // xn dropped: row-constant
            bool c1 = dA < d1A, c2 = dA < d2A;
            d2A = c1 ? d1A : (c2 ? dA : d2A);
            i2A = c1 ? i1A : (c2 ? ki : i2A);
            d1A = c1 ? dA : d1A;
            i1A = c1 ? ki : i1A;
            float dB = fmaf(-2.f, aB[r], en);
            bool e1c = dB < d1B, e2c = dB < d2B;
            d2B = e1c ? d1B : (e2c ? dB : d2B);
            i2B = e1c ? i1B : (e2c ? ki : i2B);
            d1B = e1c ? dB : d1B;
            i1B = e1c ? ki : i1B;
        }
    }

    merge_top2(d1A, i1A, d2A, i2A);
    merge_top2(d1B, i1B, d2B, i2B);
    if (lane < 16) {
        cand[rowA] = make_int2(i1A, i2A);
        cand[rowB] = make_int2(i1B, i2B);
    }
}

// exact fp32 rescore of top-2 + full epilogue (loss, hist, quantized, one-hot)
__global__ __launch_bounds__(256) void vq_merge(const float* __restrict__ x,
                                                const float* __restrict__ emb,
                                                const float* __restrict__ norms,
                                                const int2* __restrict__ cand,
                                                float* __restrict__ out,
                                                unsigned int* __restrict__ counts,
                                                float* __restrict__ loss_acc) {
    float* __restrict__ qout = out + 1;
    float* __restrict__ enc  = out + 8388610;
    int i = blockIdx.x * 256 + threadIdx.x;
    int2 cd = cand[i];

    const float4* xr = (const float4*)(x + (size_t)i * DIM);
    float4 xv[16];
#pragma unroll
    for (int j = 0; j < 16; ++j) xv[j] = xr[j];

    float xn;
    {
        float a0 = 0.f, a1 = 0.f, a2 = 0.f, a3 = 0.f;
#pragma unroll
        for (int j = 0; j < 16; ++j) {
            a0 = fmaf(xv[j].x, xv[j].x, a0);
            a1 = fmaf(xv[j].y, xv[j].y, a1);
            a2 = fmaf(xv[j].z, xv[j].z, a2);
            a3 = fmaf(xv[j].w, xv[j].w, a3);
        }
        xn = (a0 + a1) + (a2 + a3);
    }

    float dA, dB;
    {
        const float4* eA = (const float4*)(emb + (size_t)cd.x * DIM);
        const float4* eB = (const float4*)(emb + (size_t)cd.y * DIM);
        float a0 = 0.f, a1 = 0.f, a2 = 0.f, a3 = 0.f;
        float b0 = 0.f, b1 = 0.f, b2 = 0.f, b3 = 0.f;
#pragma unroll
        for (int j = 0; j < 16; ++j) {
            float4 ev = eA[j], fv = eB[j];
            a0 = fmaf(xv[j].x, ev.x, a0);
            a1 = fmaf(xv[j].y, ev.y, a1);
            a2 = fmaf(xv[j].z, ev.z, a2);
            a3 = fmaf(xv[j].w, ev.w, a3);
            b0 = fmaf(xv[j].x, fv.x, b0);
            b1 = fmaf(xv[j].y, fv.y, b1);
            b2 = fmaf(xv[j].z, fv.z, b2);
            b3 = fmaf(xv[j].w, fv.w, b3);
        }
        float dotA = (a0 + a1) + (a2 + a3);
        float dotB = (b0 + b1) + (b2 + b3);
        dA = fmaf(-2.f, dotA, xn) + norms[cd.x];
        dB = fmaf(-2.f, dotB, xn) + norms[cd.y];
    }
    // np.argmin keeps FIRST minimum -> ties to smaller index
    int bi = (dB < dA || (dB == dA && cd.y < cd.x)) ? cd.y : cd.x;

    // loss contribution: sum (x - e_bi)^2
    float err;
    {
        const float4* eb = (const float4*)(emb + (size_t)bi * DIM);
        float a0 = 0.f, a1 = 0.f, a2 = 0.f, a3 = 0.f;
#pragma unroll
        for (int j = 0; j < 16; ++j) {
            float4 ev = eb[j];
            float e0 = xv[j].x - ev.x, e1 = xv[j].y - ev.y;
            float e2 = xv[j].z - ev.z, e3 = xv[j].w - ev.w;
            a0 = fmaf(e0, e0, a0);
            a1 = fmaf(e1, e1, a1);
            a2 = fmaf(e2, e2, a2);
            a3 = fmaf(e3, e3, a3);
        }
        err = (a0 + a1) + (a2 + a3);
    }
#pragma unroll
    for (int off = 32; off > 0; off >>= 1) err += __shfl_down(err, off);
    if ((threadIdx.x & 63) == 0) atomicAdd(loss_acc, err);

    // histogram + cooperative quantized write
    __shared__ unsigned int hist[KCB];
    __shared__ int sbi[256];
    sbi[threadIdx.x] = bi;
    for (int j = threadIdx.x; j < KCB; j += 256) hist[j] = 0u;
    __syncthreads();
    atomicAdd(&hist[bi], 1u);
    __syncthreads();
    for (int j = threadIdx.x; j < KCB; j += 256) {
        unsigned int c = hist[j];
        if (c) atomicAdd(&counts[j], c);
    }
    int base_row = blockIdx.x * 256;
#pragma unroll 4
    for (int j = threadIdx.x; j < 256 * DIM; j += 256) {
        int r = j >> 6, cc = j & 63;
        qout[(size_t)(base_row + r) * DIM + cc] = emb[(size_t)sbi[r] * DIM + cc];
    }

    // one-hot scatter (encodings zeroed by fill role in vq_main)
    enc[(size_t)i * KCB + bi] = 1.0f;
}

__global__ __launch_bounds__(512) void vq_final(const unsigned int* __restrict__ counts,
                                                const float* __restrict__ loss_acc,
                                                float* __restrict__ out) {
    __shared__ float red[512];
    int t = threadIdx.x;
    float p = (float)counts[t] * (1.0f / 131072.0f);
    red[t] = p * logf(p + 1e-10f);
    __syncthreads();
    for (int s = 256; s > 0; s >>= 1) {
        if (t < s) red[t] += red[t + s];
        __syncthreads();
    }
    if (t == 0) {
        out[8388609] = expf(-red[0]);
        out[0] = 1.25f * (*loss_acc) * (1.0f / 8388608.0f);
    }
}

extern "C" void kernel_launch(void* const* d_in, const int* in_sizes, int n_in,
                              void* d_out, int out_size, void* d_ws, size_t ws_size,
                              hipStream_t stream) {
    const float* x   = (const float*)d_in[0];
    const float* emb = (const float*)d_in[1];
    float* out = (float*)d_out;
    char* ws = (char*)d_ws;
    unsigned int* counts = (unsigned int*)ws;
    float* loss_acc = (float*)(ws + 2048);
    float* norms = (float*)(ws + 4096);
    int2* cnd = (int2*)(ws + 8192);
    unsigned short* e_bf = (unsigned short*)(ws + 8192 + 2 * NVEC * 4);

    vq_prep<<<8, 256, 0, stream>>>(emb, norms, e_bf, counts, loss_acc);
    vq_main<<<2048, 256, 0, stream>>>(x, e_bf, norms, out, cnd);
    vq_merge<<<512, 256, 0, stream>>>(x, emb, norms, cnd, out, counts, loss_acc);
    vq_final<<<1, 512, 0, stream>>>(counts, loss_acc, out);
}

// Round 6
// 120.589 us; speedup vs baseline: 4.0577x; 1.6619x over previous
//
#include <hip/hip_runtime.h>
#include <math.h>

#define NVEC 131072
#define DIM 64
#define KCB 512
#define FLT_BIG 3.402823466e38f

typedef __attribute__((ext_vector_type(8))) short bf16x8;
typedef __attribute__((ext_vector_type(4))) float f32x4;

// d_out layout (floats): [0] loss | [1..8388608] quantized | [8388609] perplexity
//                        | [8388610 ..] encodings (131072 x 512)
// d_ws layout (bytes):
//   [0,2048)         u32 counts[512]
//   [2048]           float loss_acc
//   [4096,6144)      float norms[512]
//   [8192, +128K)    ushort e_bf[512][128]      (row: eh[64] | el[64])

__device__ inline unsigned int bf16_rne(float f) {
    unsigned int u = __float_as_uint(f);
    u += 0x7fffu + ((u >> 16) & 1u);
    return u >> 16;
}

__device__ inline void split_frag(float4 p0, float4 p1, bf16x8& hi, bf16x8& lo) {
    union { bf16x8 v; unsigned int u[4]; } H, L;
    float f[8] = {p0.x, p0.y, p0.z, p0.w, p1.x, p1.y, p1.z, p1.w};
    unsigned int h[8];
    float r[8];
#pragma unroll
    for (int j = 0; j < 8; ++j) {
        h[j] = bf16_rne(f[j]);
        r[j] = f[j] - __uint_as_float(h[j] << 16);
    }
#pragma unroll
    for (int j = 0; j < 4; ++j) {
        H.u[j] = h[2 * j] | (h[2 * j + 1] << 16);
        L.u[j] = bf16_rne(r[2 * j]) | (bf16_rne(r[2 * j + 1]) << 16);
    }
    hi = H.v;
    lo = L.v;
}

// merge two top-2 lists across lane groups (k-subsets are disjoint)
__device__ inline void merge_top2(float& d1, int& i1, float& d2, int& i2) {
#pragma unroll
    for (int m = 16; m <= 32; m <<= 1) {
        float e1 = __shfl_xor(d1, m), e2 = __shfl_xor(d2, m);
        int j1 = __shfl_xor(i1, m), j2 = __shfl_xor(i2, m);
        bool af = (d1 < e1) || (d1 == e1 && i1 < j1);
        float w2 = af ? d2 : e2; int w2i = af ? i2 : j2;   // winner's runner-up
        float lb = af ? e1 : d1; int lbi = af ? j1 : i1;   // loser's best
        bool bs = (w2 < lb) || (w2 == lb && w2i < lbi);
        d1 = af ? d1 : e1; i1 = af ? i1 : j1;
        d2 = bs ? w2 : lb; i2 = bs ? w2i : lbi;
    }
}

// prep: norms (fp32), bf16 hi/lo codebook, zero counts/loss
__global__ __launch_bounds__(256) void vq_prep(const float* __restrict__ emb,
                                               float* __restrict__ norms,
                                               unsigned short* __restrict__ e_bf,
                                               unsigned int* __restrict__ counts,
                                               float* __restrict__ loss_acc) {
    int gid = blockIdx.x * 256 + threadIdx.x;   // 0..2047
    int row = gid >> 2, part = gid & 3, d0 = part * 16;
    const float* e = emb + row * DIM + d0;
    float s = 0.f;
#pragma unroll
    for (int d = 0; d < 16; ++d) s = fmaf(e[d], e[d], s);
    s += __shfl_xor(s, 1);
    s += __shfl_xor(s, 2);
    if (part == 0) norms[row] = s;
#pragma unroll
    for (int d = 0; d < 16; ++d) {
        float f = e[d];
        unsigned int h = bf16_rne(f);
        float r = f - __uint_as_float(h << 16);
        e_bf[row * 128 + d0 + d] = (unsigned short)h;
        e_bf[row * 128 + 64 + d0 + d] = (unsigned short)bf16_rne(r);
    }
    if (gid < KCB) counts[gid] = 0u;
    if (gid == 0) *loss_acc = 0.f;
}

// fused: MFMA top-2 argmin (+ overlapped zeroing of own encodings rows),
// exact fp32 rescore, loss, histogram, quantized + one-hot writes.
__global__ __launch_bounds__(256) void vq_fused(const float* __restrict__ x,
                                                const float* __restrict__ emb,
                                                const unsigned short* __restrict__ e_bf,
                                                const float* __restrict__ norms,
                                                float* __restrict__ out,
                                                unsigned int* __restrict__ counts,
                                                float* __restrict__ loss_acc) {
    float* __restrict__ qout = out + 1;
    float* __restrict__ enc  = out + 8388610;
    int tid = threadIdx.x;
    int wave = tid >> 6;
    int lane = tid & 63;
    int nl = lane & 15, kg = lane >> 4;
    int rowA = blockIdx.x * 128 + wave * 32 + nl;
    int rowB = rowA + 16;

    __shared__ unsigned int hist[KCB];
    __shared__ int2 scand[128];
    __shared__ int sbi[128];
    __shared__ float serr[128];
    for (int j = tid; j < KCB; j += 256) hist[j] = 0u;

    // B-frags (x side): lane col = x-row, k = kg*8+e (+32 per kslice)
    bf16x8 xhA[2], xlA[2], xhB[2], xlB[2];
    {
        const float* xA = x + (size_t)rowA * DIM;
        const float* xB = x + (size_t)rowB * DIM;
#pragma unroll
        for (int ks = 0; ks < 2; ++ks) {
            const float4* pA = (const float4*)(xA + ks * 32 + kg * 8);
            const float4* pB = (const float4*)(xB + ks * 32 + kg * 8);
            split_frag(pA[0], pA[1], xhA[ks], xlA[ks]);
            split_frag(pB[0], pB[1], xhB[ks], xlB[ks]);
        }
    }

    float d1A = FLT_BIG, d2A = FLT_BIG, d1B = FLT_BIG, d2B = FLT_BIG;
    int i1A = 0, i2A = 0, i1B = 0, i2B = 0;

    // overlapped zero-fill of this block's 128 encodings rows (256 KB):
    // 4 float2 stores per thread per t-iteration, coalesced, independent of MFMA
    float2* enc2 = (float2*)enc;                       // 8B-aligned base
    size_t zbase = (size_t)blockIdx.x * 32768 + tid;   // in float2 units
    float2 zz; zz.x = 0.f; zz.y = 0.f;

    const unsigned short* ebl = e_bf + (size_t)nl * 128;
#pragma unroll 2
    for (int t = 0; t < 32; ++t) {
        const unsigned short* eb = ebl + t * 2048;  // codebook row t*16+nl
        bf16x8 eh0 = *(const bf16x8*)(eb + kg * 8);
        bf16x8 eh1 = *(const bf16x8*)(eb + 32 + kg * 8);
        bf16x8 el0 = *(const bf16x8*)(eb + 64 + kg * 8);
        bf16x8 el1 = *(const bf16x8*)(eb + 96 + kg * 8);

        enc2[zbase + t * 1024 + 0]   = zz;
        enc2[zbase + t * 1024 + 256] = zz;
        enc2[zbase + t * 1024 + 512] = zz;
        enc2[zbase + t * 1024 + 768] = zz;

        f32x4 aA = {}, aB = {};
        // dot = xh*eh + xh*el + xl*eh  (A = e-side, B = x-side)
        aA = __builtin_amdgcn_mfma_f32_16x16x32_bf16(eh0, xhA[0], aA, 0, 0, 0);
        aA = __builtin_amdgcn_mfma_f32_16x16x32_bf16(eh1, xhA[1], aA, 0, 0, 0);
        aA = __builtin_amdgcn_mfma_f32_16x16x32_bf16(el0, xhA[0], aA, 0, 0, 0);
        aA = __builtin_amdgcn_mfma_f32_16x16x32_bf16(el1, xhA[1], aA, 0, 0, 0);
        aA = __builtin_amdgcn_mfma_f32_16x16x32_bf16(eh0, xlA[0], aA, 0, 0, 0);
        aA = __builtin_amdgcn_mfma_f32_16x16x32_bf16(eh1, xlA[1], aA, 0, 0, 0);

        aB = __builtin_amdgcn_mfma_f32_16x16x32_bf16(eh0, xhB[0], aB, 0, 0, 0);
        aB = __builtin_amdgcn_mfma_f32_16x16x32_bf16(eh1, xhB[1], aB, 0, 0, 0);
        aB = __builtin_amdgcn_mfma_f32_16x16x32_bf16(el0, xhB[0], aB, 0, 0, 0);
        aB = __builtin_amdgcn_mfma_f32_16x16x32_bf16(el1, xhB[1], aB, 0, 0, 0);
        aB = __builtin_amdgcn_mfma_f32_16x16x32_bf16(eh0, xlB[0], aB, 0, 0, 0);
        aB = __builtin_amdgcn_mfma_f32_16x16x32_bf16(eh1, xlB[1], aB, 0, 0, 0);

        // C/D: col=lane&15 (x-row), row=(lane>>4)*4+reg (e-idx) [m89-verified]
        int krow0 = t * 16 + kg * 4;
#pragma unroll
        for (int r = 0; r < 4; ++r) {
            float en = norms[krow0 + r];
            int ki = krow0 + r;
            float dA = fmaf(-2.f, aA[r], en);   // xn dropped: row-constant
            bool c1 = dA < d1A, c2 = dA < d2A;
            d2A = c1 ? d1A : (c2 ? dA : d2A);
            i2A = c1 ? i1A : (c2 ? ki : i2A);
            d1A = c1 ? dA : d1A;
            i1A = c1 ? ki : i1A;
            float dB = fmaf(-2.f, aB[r], en);
            bool e1c = dB < d1B, e2c = dB < d2B;
            d2B = e1c ? d1B : (e2c ? dB : d2B);
            i2B = e1c ? i1B : (e2c ? ki : i2B);
            d1B = e1c ? dB : d1B;
            i1B = e1c ? ki : i1B;
        }
    }

    merge_top2(d1A, i1A, d2A, i2A);
    merge_top2(d1B, i1B, d2B, i2B);
    if (lane < 16) {
        scand[wave * 32 + nl] = make_int2(i1A, i2A);
        scand[wave * 32 + nl + 16] = make_int2(i1B, i2B);
    }
    __syncthreads();   // drains the zero stores too (vmcnt(0) before barrier)

    // ---- exact fp32 rescore: one thread per row
    if (tid < 128) {
        int grow = blockIdx.x * 128 + tid;
        int2 cd = scand[tid];
        const float4* xr = (const float4*)(x + (size_t)grow * DIM);
        float4 xv[16];
#pragma unroll
        for (int j = 0; j < 16; ++j) xv[j] = xr[j];

        float xn;
        {
            float a0 = 0.f, a1 = 0.f, a2 = 0.f, a3 = 0.f;
#pragma unroll
            for (int j = 0; j < 16; ++j) {
                a0 = fmaf(xv[j].x, xv[j].x, a0);
                a1 = fmaf(xv[j].y, xv[j].y, a1);
                a2 = fmaf(xv[j].z, xv[j].z, a2);
                a3 = fmaf(xv[j].w, xv[j].w, a3);
            }
            xn = (a0 + a1) + (a2 + a3);
        }
        float dA, dB;
        {
            const float4* eA = (const float4*)(emb + (size_t)cd.x * DIM);
            const float4* eB = (const float4*)(emb + (size_t)cd.y * DIM);
            float a0 = 0.f, a1 = 0.f, a2 = 0.f, a3 = 0.f;
            float b0 = 0.f, b1 = 0.f, b2 = 0.f, b3 = 0.f;
#pragma unroll
            for (int j = 0; j < 16; ++j) {
                float4 ev = eA[j], fv = eB[j];
                a0 = fmaf(xv[j].x, ev.x, a0);
                a1 = fmaf(xv[j].y, ev.y, a1);
                a2 = fmaf(xv[j].z, ev.z, a2);
                a3 = fmaf(xv[j].w, ev.w, a3);
                b0 = fmaf(xv[j].x, fv.x, b0);
                b1 = fmaf(xv[j].y, fv.y, b1);
                b2 = fmaf(xv[j].z, fv.z, b2);
                b3 = fmaf(xv[j].w, fv.w, b3);
            }
            float dotA = (a0 + a1) + (a2 + a3);
            float dotB = (b0 + b1) + (b2 + b3);
            dA = fmaf(-2.f, dotA, xn) + norms[cd.x];
            dB = fmaf(-2.f, dotB, xn) + norms[cd.y];
        }
        // np.argmin keeps FIRST minimum -> ties to smaller index
        int bi = (dB < dA || (dB == dA && cd.y < cd.x)) ? cd.y : cd.x;

        float err;
        {
            const float4* ebv = (const float4*)(emb + (size_t)bi * DIM);
            float a0 = 0.f, a1 = 0.f, a2 = 0.f, a3 = 0.f;
#pragma unroll
            for (int j = 0; j < 16; ++j) {
                float4 ev = ebv[j];
                float e0 = xv[j].x - ev.x, e1 = xv[j].y - ev.y;
                float e2 = xv[j].z - ev.z, e3 = xv[j].w - ev.w;
                a0 = fmaf(e0, e0, a0);
                a1 = fmaf(e1, e1, a1);
                a2 = fmaf(e2, e2, a2);
                a3 = fmaf(e3, e3, a3);
            }
            err = (a0 + a1) + (a2 + a3);
        }
        sbi[tid] = bi;
        serr[tid] = err;
        atomicAdd(&hist[bi], 1u);
        // one-hot: this block zeroed this row before the barrier
        enc[(size_t)grow * KCB + bi] = 1.0f;
    }
    __syncthreads();

    // flush histogram
    for (int j = tid; j < KCB; j += 256) {
        unsigned int c = hist[j];
        if (c) atomicAdd(&counts[j], c);
    }
    // loss reduction over 128 row errors
    if (tid < 64) {
        float v = serr[tid] + serr[tid + 64];
#pragma unroll
        for (int off = 32; off > 0; off >>= 1) v += __shfl_down(v, off);
        if (tid == 0) atomicAdd(loss_acc, v);
    }
    // cooperative quantized write (dword stores; qout is out+1, 4B-aligned)
#pragma unroll 4
    for (int j = 0; j < 32; ++j) {
        int f = j * 256 + tid;          // 0..8191
        int r = f >> 6, c = f & 63;
        qout[((size_t)blockIdx.x * 128 + r) * DIM + c] =
            emb[(size_t)sbi[r] * DIM + c];
    }
}

__global__ __launch_bounds__(512) void vq_final(const unsigned int* __restrict__ counts,
                                                const float* __restrict__ loss_acc,
                                                float* __restrict__ out) {
    __shared__ float red[512];
    int t = threadIdx.x;
    float p = (float)counts[t] * (1.0f / 131072.0f);
    red[t] = p * logf(p + 1e-10f);
    __syncthreads();
    for (int s = 256; s > 0; s >>= 1) {
        if (t < s) red[t] += red[t + s];
        __syncthreads();
    }
    if (t == 0) {
        out[8388609] = expf(-red[0]);
        out[0] = 1.25f * (*loss_acc) * (1.0f / 8388608.0f);
    }
}

extern "C" void kernel_launch(void* const* d_in, const int* in_sizes, int n_in,
                              void* d_out, int out_size, void* d_ws, size_t ws_size,
                              hipStream_t stream) {
    const float* x   = (const float*)d_in[0];
    const float* emb = (const float*)d_in[1];
    float* out = (float*)d_out;
    char* ws = (char*)d_ws;
    unsigned int* counts = (unsigned int*)ws;
    float* loss_acc = (float*)(ws + 2048);
    float* norms = (float*)(ws + 4096);
    unsigned short* e_bf = (unsigned short*)(ws + 8192);

    vq_prep<<<8, 256, 0, stream>>>(emb, norms, e_bf, counts, loss_acc);
    vq_fused<<<1024, 256, 0, stream>>>(x, emb, e_bf, norms, out, counts, loss_acc);
    vq_final<<<1, 512, 0, stream>>>(counts, loss_acc, out);
}